// Round 7
// baseline (136.975 us; speedup 1.0000x reference)
//
#include <hip/hip_runtime.h>
#include <hip/hip_bf16.h>
#include <stdint.h>

// SymmetricTensorProduct: n=8192, MUL=128, DIM_IN=512
//   out_s[z,u] = (1/16)*xs[z,u]*S[z,u] + (1/(16*sqrt3))*sum_i V_i[z,u]*xv[z,u,i]
//   t[z,v,w]   = sum_u xs[z,u]*w_sv[u,v,w]
//   out_v[z,w,i] = (1/128)*sum_v t[z,v,w]*xv[z,v,i]
//
// Round-7 outv: r6 skeleton (fragment-order Wt, counted vmcnt, 4-buffer
// rotation) with 4 v per phase: 32 barriers, 32 MFMA/wave/phase, LDS 128KB
// dynamic (4 x 32KB), vmcnt(16) depth-2. xv via uint pair-loads from
// xvq[i][z][v]. Helpers: outs split over u-halves (grid 1024), prep_cast
// re-tiled (256 transpose blocks).

#define NZ 8192
#define NM (8192*128)

typedef __attribute__((ext_vector_type(8))) short bf16x8;
typedef __attribute__((ext_vector_type(4))) float f32x4;

__device__ __forceinline__ ushort f2bf(float f) {
  uint32_t u = __builtin_bit_cast(uint32_t, f);
  u += 0x7fffu + ((u >> 16) & 1u);   // RNE
  return (ushort)(u >> 16);
}
__device__ __forceinline__ void gload16(const void* g, void* l) {
  __builtin_amdgcn_global_load_lds((const __attribute__((address_space(1))) void*)g,
                                   (__attribute__((address_space(3))) void*)l, 16, 0, 0);
}

// ---------------- prep: xs_bf + xvq[i][z][v] + w casts ----------------------
__global__ __launch_bounds__(256) void prep_cast(
    const float* __restrict__ x, const float* __restrict__ w_ss,
    const float* __restrict__ w_vv, ushort* __restrict__ xs_bf,
    ushort* __restrict__ xvq, ushort* __restrict__ wssb,
    ushort* __restrict__ wvvb) {
  int bid = blockIdx.x, tid = threadIdx.x;
  if (bid < 256) {
    __shared__ ushort tile[3 * 32 * 128];   // [i][zloc][v]
    int z0 = bid * 32;
#pragma unroll
    for (int it = 0; it < 16; ++it) {
      int idx = it * 256 + tid;             // 0..4095
      int zloc = idx >> 7, c4 = idx & 127;
      float4 f = *(const float4*)(x + (size_t)(z0 + zloc) * 512 + c4 * 4);
      if (c4 < 32) {
        ushort4 o;
        o.x = f2bf(f.x); o.y = f2bf(f.y); o.z = f2bf(f.z); o.w = f2bf(f.w);
        *(ushort4*)(xs_bf + (size_t)(z0 + zloc) * 128 + c4 * 4) = o;
      } else {
        int c = c4 * 4 - 128;               // 0..383
        float vals[4] = {f.x, f.y, f.z, f.w};
#pragma unroll
        for (int e = 0; e < 4; ++e) {
          int cc = c + e, v = cc / 3, i = cc - 3 * v;
          tile[i * 4096 + zloc * 128 + v] = f2bf(vals[e]);
        }
      }
    }
    __syncthreads();
#pragma unroll
    for (int it = 0; it < 6; ++it) {
      int idx = it * 256 + tid;             // 0..1535
      int i = idx >> 9, r = idx & 511;
      int zloc = r >> 4, oct = r & 15;
      *(bf16x8*)(xvq + ((size_t)i * NZ + z0 + zloc) * 128 + oct * 8) =
          *(const bf16x8*)(tile + i * 4096 + zloc * 128 + oct * 8);
    }
  } else {
    int k = (bid - 256) * 256 + tid;
    if (k < 16384) wssb[k] = f2bf(w_ss[k]);
    else wvvb[k - 16384] = f2bf(w_vv[k - 16384]);
  }
}

// ---- prep: w_sv[u][v][w] -> Wt fragment order [v][wc][wg][kk][l][e] --------
__global__ __launch_bounds__(256) void prep_wt(const float* __restrict__ w_sv,
                                               ushort* __restrict__ Wt) {
  __shared__ ushort tile[4096];
  int v = blockIdx.x >> 2, wc = blockIdx.x & 3;
  int t = threadIdx.x;
  int u = t >> 1, wh = t & 1;
  const float* src = w_sv + (size_t)u * 16384 + v * 128 + wc * 32 + wh * 16;
  int kk = u >> 5, lg = (u >> 3) & 3, e = u & 7;
#pragma unroll
  for (int ww = 0; ww < 16; ++ww)
    tile[wh * 2048 + kk * 512 + (lg * 16 + ww) * 8 + e] = f2bf(src[ww]);
  __syncthreads();
  bf16x8* dst = (bf16x8*)(Wt + ((size_t)v * 4 + wc) * 4096);
  const bf16x8* s = (const bf16x8*)tile;
  dst[t] = s[t];
  dst[t + 256] = s[t + 256];
}

// ---------------- out_s via MFMA (u-half split, grid 1024) ------------------
__global__ __launch_bounds__(128) void outs_mfma(
    const float* __restrict__ x, const ushort* __restrict__ xs_bf,
    const ushort* __restrict__ wssb, const ushort* __restrict__ wvvb,
    float* __restrict__ out) {
  int bid = blockIdx.x;
  int uh = bid & 3, zb = bid >> 2;
  int tid = threadIdx.x, wid = tid >> 6, l = tid & 63;
  int lr = l & 15, lg = l >> 4;
  int z = zb * 32 + wid * 16 + lr;
  const float* xrow = x + (size_t)z * 512;

  bf16x8 bs[4], b0[4], b1[4], b2[4];
#pragma unroll
  for (int kk = 0; kk < 4; ++kk) {
    int k0 = kk * 32 + lg * 8;
    bs[kk] = *(const bf16x8*)(xs_bf + (size_t)z * 128 + k0);
    float4 f[6];
    const float4* src = (const float4*)(xrow + 128 + 3 * k0);
#pragma unroll
    for (int q = 0; q < 6; ++q) f[q] = src[q];
    const float* ff = (const float*)f;
#pragma unroll
    for (int jj = 0; jj < 8; ++jj) {
      b0[kk][jj] = (short)f2bf(ff[3 * jj + 0]);
      b1[kk][jj] = (short)f2bf(ff[3 * jj + 1]);
      b2[kk][jj] = (short)f2bf(ff[3 * jj + 2]);
    }
  }
#pragma unroll
  for (int uu = 0; uu < 2; ++uu) {
    int u0 = (uh * 2 + uu) * 16;
    f32x4 css = {0.f, 0.f, 0.f, 0.f};
    f32x4 cv0 = {0.f, 0.f, 0.f, 0.f};
    f32x4 cv1 = {0.f, 0.f, 0.f, 0.f};
    f32x4 cv2 = {0.f, 0.f, 0.f, 0.f};
#pragma unroll
    for (int kk = 0; kk < 4; ++kk) {
      int k0 = kk * 32 + lg * 8;
      bf16x8 as = *(const bf16x8*)(wssb + (size_t)(u0 + lr) * 128 + k0);
      bf16x8 av = *(const bf16x8*)(wvvb + (size_t)(u0 + lr) * 128 + k0);
      css = __builtin_amdgcn_mfma_f32_16x16x32_bf16(as, bs[kk], css, 0, 0, 0);
      cv0 = __builtin_amdgcn_mfma_f32_16x16x32_bf16(av, b0[kk], cv0, 0, 0, 0);
      cv1 = __builtin_amdgcn_mfma_f32_16x16x32_bf16(av, b1[kk], cv1, 0, 0, 0);
      cv2 = __builtin_amdgcn_mfma_f32_16x16x32_bf16(av, b2[kk], cv2, 0, 0, 0);
    }
#pragma unroll
    for (int r = 0; r < 4; ++r) {
      int u = u0 + lg * 4 + r;
      float xsv = xrow[u];
      const float* xvu = xrow + 128 + 3 * u;
      out[(size_t)z * 512 + u] =
          0.0625f * xsv * css[r] +
          0.036084391824351615f * (cv0[r] * xvu[0] + cv1[r] * xvu[1] + cv2[r] * xvu[2]);
    }
  }
}

// ---------------- out_v -----------------------------------------------------
// grid 256 = 64 zb(128z) x 4 wc(32w); 1 block/CU. 8 waves: wg=wid&1, zg=wid>>1.
// Wave: 32z (2 n-tiles) x 16w x all v. Phase = 4 v (tile T): 4 gload16 +
// 12 xv uint loads, 16 ds_read_b128, 32 MFMA, 96 FMA; vmcnt(16) depth-2;
// 4-buffer LDS rotation (128KB dynamic).

#define OUTV_PHASE(T, CUR, NXT, XC, XN)                                        \
  do {                                                                         \
    asm volatile("s_waitcnt vmcnt(16)" ::: "memory");                          \
    __builtin_amdgcn_s_barrier();                                              \
    __builtin_amdgcn_sched_barrier(0);                                         \
    int ts = (T) + 2; if (ts > 31) ts = 31;                                    \
    _Pragma("unroll")                                                          \
    for (int vv = 0; vv < 4; ++vv)                                             \
      gload16(Wt + ((size_t)(4 * ts + vv) * 4 + wc) * 4096 + tid * 8,          \
              lds + (NXT) * 32768 + vv * 8192 + tid * 16);                     \
    _Pragma("unroll")                                                          \
    for (int n2 = 0; n2 < 2; ++n2)                                             \
      _Pragma("unroll")                                                        \
      for (int i2 = 0; i2 < 3; ++i2)                                           \
        _Pragma("unroll")                                                      \
        for (int vp = 0; vp < 2; ++vp)                                         \
          XN[(n2 * 3 + i2) * 2 + vp] = *(const uint*)(                         \
              xvq + ((size_t)i2 * NZ + zbase + n2 * 16) * 128 + 4 * ts + 2 * vp); \
    __builtin_amdgcn_sched_barrier(0);                                         \
    _Pragma("unroll")                                                          \
    for (int vv = 0; vv < 4; ++vv) {                                           \
      const char* ab = lds + (CUR) * 32768 + vv * 8192 + wg * 4096 + l * 16;   \
      bf16x8 a0 = *(const bf16x8*)(ab);                                        \
      bf16x8 a1 = *(const bf16x8*)(ab + 1024);                                 \
      bf16x8 a2 = *(const bf16x8*)(ab + 2048);                                 \
      bf16x8 a3 = *(const bf16x8*)(ab + 3072);                                 \
      _Pragma("unroll")                                                        \
      for (int n = 0; n < 2; ++n) {                                            \
        f32x4 tt = {0.f, 0.f, 0.f, 0.f};                                       \
        __builtin_amdgcn_s_setprio(1);                                         \
        tt = __builtin_amdgcn_mfma_f32_16x16x32_bf16(a0, b[n][0], tt, 0, 0, 0);\
        tt = __builtin_amdgcn_mfma_f32_16x16x32_bf16(a1, b[n][1], tt, 0, 0, 0);\
        tt = __builtin_amdgcn_mfma_f32_16x16x32_bf16(a2, b[n][2], tt, 0, 0, 0);\
        tt = __builtin_amdgcn_mfma_f32_16x16x32_bf16(a3, b[n][3], tt, 0, 0, 0);\
        __builtin_amdgcn_s_setprio(0);                                         \
        uint q0 = XC[(n * 3 + 0) * 2 + (vv >> 1)];                             \
        uint q1 = XC[(n * 3 + 1) * 2 + (vv >> 1)];                             \
        uint q2 = XC[(n * 3 + 2) * 2 + (vv >> 1)];                             \
        float x0, x1, x2;                                                      \
        if ((vv & 1) == 0) {                                                   \
          x0 = __builtin_bit_cast(float, q0 << 16);                            \
          x1 = __builtin_bit_cast(float, q1 << 16);                            \
          x2 = __builtin_bit_cast(float, q2 << 16);                            \
        } else {                                                               \
          x0 = __builtin_bit_cast(float, q0 & 0xffff0000u);                    \
          x1 = __builtin_bit_cast(float, q1 & 0xffff0000u);                    \
          x2 = __builtin_bit_cast(float, q2 & 0xffff0000u);                    \
        }                                                                      \
        _Pragma("unroll")                                                      \
        for (int r = 0; r < 4; ++r) {                                          \
          acc[n][r][0] += tt[r] * x0;                                          \
          acc[n][r][1] += tt[r] * x1;                                          \
          acc[n][r][2] += tt[r] * x2;                                          \
        }                                                                      \
      }                                                                        \
    }                                                                          \
  } while (0)

__global__ __launch_bounds__(512, 1) void outv_kernel(
    const ushort* __restrict__ xs_bf, const ushort* __restrict__ xvq,
    const ushort* __restrict__ Wt, float* __restrict__ out) {
  extern __shared__ char lds[];      // 4 x 32KB
  int bid = blockIdx.x;
  int wc = bid & 3, zb = bid >> 2;
  int tid = threadIdx.x;
  int wid = tid >> 6, l = tid & 63;
  int wg = wid & 1, zg = wid >> 1;
  int lr = l & 15, lg = l >> 4;
  int zbase = zb * 128 + zg * 32 + lr;     // n-tile adds 16
  int w0 = wc * 32 + wg * 16;

  // B-fragments (xs), held all kernel: 2 n-tiles x 4 k-chunks
  bf16x8 b[2][4];
#pragma unroll
  for (int n = 0; n < 2; ++n)
#pragma unroll
    for (int kk = 0; kk < 4; ++kk)
      b[n][kk] = *(const bf16x8*)(xs_bf + (size_t)(zbase + n * 16) * 128 + kk * 32 + lg * 8);
  __builtin_amdgcn_sched_barrier(0);

  uint xu0[12], xu1[12], xu2[12], xu3[12];
  // prologue: tile0 -> buf0 + xu0, tile1 -> buf1 + xu1 (16+16 vmem ops)
#pragma unroll
  for (int vv = 0; vv < 4; ++vv)
    gload16(Wt + ((size_t)(0 + vv) * 4 + wc) * 4096 + tid * 8,
            lds + vv * 8192 + tid * 16);
#pragma unroll
  for (int n2 = 0; n2 < 2; ++n2)
#pragma unroll
    for (int i2 = 0; i2 < 3; ++i2)
#pragma unroll
      for (int vp = 0; vp < 2; ++vp)
        xu0[(n2 * 3 + i2) * 2 + vp] = *(const uint*)(
            xvq + ((size_t)i2 * NZ + zbase + n2 * 16) * 128 + 2 * vp);
  __builtin_amdgcn_sched_barrier(0);
#pragma unroll
  for (int vv = 0; vv < 4; ++vv)
    gload16(Wt + ((size_t)(4 + vv) * 4 + wc) * 4096 + tid * 8,
            lds + 32768 + vv * 8192 + tid * 16);
#pragma unroll
  for (int n2 = 0; n2 < 2; ++n2)
#pragma unroll
    for (int i2 = 0; i2 < 3; ++i2)
#pragma unroll
      for (int vp = 0; vp < 2; ++vp)
        xu1[(n2 * 3 + i2) * 2 + vp] = *(const uint*)(
            xvq + ((size_t)i2 * NZ + zbase + n2 * 16) * 128 + 4 + 2 * vp);
  __builtin_amdgcn_sched_barrier(0);

  float acc[2][4][3] = {};

  for (int q = 0; q < 8; ++q) {
    OUTV_PHASE(4 * q + 0, 0, 2, xu0, xu2);
    OUTV_PHASE(4 * q + 1, 1, 3, xu1, xu3);
    OUTV_PHASE(4 * q + 2, 2, 0, xu2, xu0);
    OUTV_PHASE(4 * q + 3, 3, 1, xu3, xu1);
  }

#pragma unroll
  for (int n = 0; n < 2; ++n) {
#pragma unroll
    for (int r = 0; r < 4; ++r) {
      int z = zbase + n * 16;
      int w = w0 + lg * 4 + r;
      float* o = out + (size_t)z * 512 + 128 + 3 * w;
      o[0] = acc[n][r][0] * 0.0078125f;
      o[1] = acc[n][r][1] * 0.0078125f;
      o[2] = acc[n][r][2] * 0.0078125f;
    }
  }
}

// ---------------- launch ----------------------------------------------------
extern "C" void kernel_launch(void* const* d_in, const int* in_sizes, int n_in,
                              void* d_out, int out_size, void* d_ws, size_t ws_size,
                              hipStream_t stream) {
  const float* x    = (const float*)d_in[0];
  const float* w_ss = (const float*)d_in[1];
  const float* w_sv = (const float*)d_in[2];
  const float* w_vv = (const float*)d_in[3];
  float* out = (float*)d_out;

  char* ws = (char*)d_ws;
  ushort* xs_bf = (ushort*)ws;                                  // 2 MB
  ushort* Wt    = (ushort*)(ws + (size_t)2 * 1024 * 1024);      // 4 MB (frag order)
  ushort* xvq   = (ushort*)(ws + (size_t)6 * 1024 * 1024);      // 6 MB
  ushort* wssb  = (ushort*)(ws + (size_t)12 * 1024 * 1024);     // 32 KB
  ushort* wvvb  = (ushort*)(ws + (size_t)12 * 1024 * 1024 + 32768);

  prep_cast<<<384, 256, 0, stream>>>(x, w_ss, w_vv, xs_bf, xvq, wssb, wvvb);
  prep_wt<<<512, 256, 0, stream>>>(w_sv, Wt);
  outs_mfma<<<1024, 128, 0, stream>>>(x, xs_bf, wssb, wvvb, out);
  outv_kernel<<<256, 512, 131072, stream>>>(xs_bf, xvq, Wt, out);
}

// Round 8
// 123.710 us; speedup vs baseline: 1.1072x; 1.1072x over previous
//
#include <hip/hip_runtime.h>
#include <hip/hip_bf16.h>
#include <stdint.h>

// SymmetricTensorProduct: n=8192, MUL=128, DIM_IN=512
//   out_s[z,u] = (1/16)*xs[z,u]*S[z,u] + (1/(16*sqrt3))*sum_i V_i[z,u]*xv[z,u,i]
//   t[z,v,w]   = sum_u xs[z,u]*w_sv[u,v,w]
//   out_v[z,w,i] = (1/128)*sum_v t[z,v,w]*xv[z,v,i]
//
// Round-8 outv: r6 skeleton (fragment-order Wt, counted vmcnt, slot rotation,
// conflict-free lane-linear ds_read) at 2 blocks/CU: grid 512, 8 waves =
// 4 zg(16z) x 2 wg(16w), phase = 2 v, 4 LDS slots x 16KB (64KB dynamic),
// vmcnt(10) depth-2(+1 staging), Wt slabs padded +3 tiles (no tail branch).
// Per-thread state minimized (b16 + acc12 + xu12 VGPRs) to avoid r5/r7 spills.

#define NZ 8192
#define NM (8192*128)
#define SLAB 548864   // ushorts per wc slab: 67 tiles x 8192 (64 real + 3 pad)

typedef __attribute__((ext_vector_type(8))) short bf16x8;
typedef __attribute__((ext_vector_type(4))) float f32x4;

__device__ __forceinline__ ushort f2bf(float f) {
  uint32_t u = __builtin_bit_cast(uint32_t, f);
  u += 0x7fffu + ((u >> 16) & 1u);   // RNE
  return (ushort)(u >> 16);
}
__device__ __forceinline__ void gload16(const void* g, void* l) {
  __builtin_amdgcn_global_load_lds((const __attribute__((address_space(1))) void*)g,
                                   (__attribute__((address_space(3))) void*)l, 16, 0, 0);
}

// ---------------- prep: xs_bf + xvq[i][z][v] + w casts ----------------------
__global__ __launch_bounds__(256) void prep_cast(
    const float* __restrict__ x, const float* __restrict__ w_ss,
    const float* __restrict__ w_vv, ushort* __restrict__ xs_bf,
    ushort* __restrict__ xvq, ushort* __restrict__ wssb,
    ushort* __restrict__ wvvb) {
  int bid = blockIdx.x, tid = threadIdx.x;
  if (bid < 256) {
    __shared__ ushort tile[3 * 32 * 128];   // [i][zloc][v]
    int z0 = bid * 32;
#pragma unroll
    for (int it = 0; it < 16; ++it) {
      int idx = it * 256 + tid;             // 0..4095
      int zloc = idx >> 7, c4 = idx & 127;
      float4 f = *(const float4*)(x + (size_t)(z0 + zloc) * 512 + c4 * 4);
      if (c4 < 32) {
        ushort4 o;
        o.x = f2bf(f.x); o.y = f2bf(f.y); o.z = f2bf(f.z); o.w = f2bf(f.w);
        *(ushort4*)(xs_bf + (size_t)(z0 + zloc) * 128 + c4 * 4) = o;
      } else {
        int c = c4 * 4 - 128;               // 0..383
        float vals[4] = {f.x, f.y, f.z, f.w};
#pragma unroll
        for (int e = 0; e < 4; ++e) {
          int cc = c + e, v = cc / 3, i = cc - 3 * v;
          tile[i * 4096 + zloc * 128 + v] = f2bf(vals[e]);
        }
      }
    }
    __syncthreads();
#pragma unroll
    for (int it = 0; it < 6; ++it) {
      int idx = it * 256 + tid;             // 0..1535
      int i = idx >> 9, r = idx & 511;
      int zloc = r >> 4, oct = r & 15;
      *(bf16x8*)(xvq + ((size_t)i * NZ + z0 + zloc) * 128 + oct * 8) =
          *(const bf16x8*)(tile + i * 4096 + zloc * 128 + oct * 8);
    }
  } else {
    int k = (bid - 256) * 256 + tid;
    if (k < 16384) wssb[k] = f2bf(w_ss[k]);
    else wvvb[k - 16384] = f2bf(w_vv[k - 16384]);
  }
}

// ---- prep: w_sv[u][v][w] -> Wt [wc][v/2][v&1][wg][kk][l][e] (padded slabs) -
__global__ __launch_bounds__(256) void prep_wt(const float* __restrict__ w_sv,
                                               ushort* __restrict__ Wt) {
  __shared__ ushort tile[4096];
  int v = blockIdx.x >> 2, wc = blockIdx.x & 3;
  int t = threadIdx.x;
  int u = t >> 1, wh = t & 1;
  const float* src = w_sv + (size_t)u * 16384 + v * 128 + wc * 32 + wh * 16;
  int kk = u >> 5, lg = (u >> 3) & 3, e = u & 7;
#pragma unroll
  for (int ww = 0; ww < 16; ++ww)
    tile[wh * 2048 + kk * 512 + (lg * 16 + ww) * 8 + e] = f2bf(src[ww]);
  __syncthreads();
  bf16x8* dst = (bf16x8*)(Wt + (size_t)wc * SLAB + (size_t)(v >> 1) * 8192 +
                          (v & 1) * 4096);
  const bf16x8* s = (const bf16x8*)tile;
  dst[t] = s[t];
  dst[t + 256] = s[t + 256];
}

// ---------------- out_s via MFMA (u-half split, grid 1024) ------------------
__global__ __launch_bounds__(128) void outs_mfma(
    const float* __restrict__ x, const ushort* __restrict__ xs_bf,
    const ushort* __restrict__ wssb, const ushort* __restrict__ wvvb,
    float* __restrict__ out) {
  int bid = blockIdx.x;
  int uh = bid & 3, zb = bid >> 2;
  int tid = threadIdx.x, wid = tid >> 6, l = tid & 63;
  int lr = l & 15, lg = l >> 4;
  int z = zb * 32 + wid * 16 + lr;
  const float* xrow = x + (size_t)z * 512;

  bf16x8 bs[4], b0[4], b1[4], b2[4];
#pragma unroll
  for (int kk = 0; kk < 4; ++kk) {
    int k0 = kk * 32 + lg * 8;
    bs[kk] = *(const bf16x8*)(xs_bf + (size_t)z * 128 + k0);
    float4 f[6];
    const float4* src = (const float4*)(xrow + 128 + 3 * k0);
#pragma unroll
    for (int q = 0; q < 6; ++q) f[q] = src[q];
    const float* ff = (const float*)f;
#pragma unroll
    for (int jj = 0; jj < 8; ++jj) {
      b0[kk][jj] = (short)f2bf(ff[3 * jj + 0]);
      b1[kk][jj] = (short)f2bf(ff[3 * jj + 1]);
      b2[kk][jj] = (short)f2bf(ff[3 * jj + 2]);
    }
  }
#pragma unroll
  for (int uu = 0; uu < 2; ++uu) {
    int u0 = (uh * 2 + uu) * 16;
    f32x4 css = {0.f, 0.f, 0.f, 0.f};
    f32x4 cv0 = {0.f, 0.f, 0.f, 0.f};
    f32x4 cv1 = {0.f, 0.f, 0.f, 0.f};
    f32x4 cv2 = {0.f, 0.f, 0.f, 0.f};
#pragma unroll
    for (int kk = 0; kk < 4; ++kk) {
      int k0 = kk * 32 + lg * 8;
      bf16x8 as = *(const bf16x8*)(wssb + (size_t)(u0 + lr) * 128 + k0);
      bf16x8 av = *(const bf16x8*)(wvvb + (size_t)(u0 + lr) * 128 + k0);
      css = __builtin_amdgcn_mfma_f32_16x16x32_bf16(as, bs[kk], css, 0, 0, 0);
      cv0 = __builtin_amdgcn_mfma_f32_16x16x32_bf16(av, b0[kk], cv0, 0, 0, 0);
      cv1 = __builtin_amdgcn_mfma_f32_16x16x32_bf16(av, b1[kk], cv1, 0, 0, 0);
      cv2 = __builtin_amdgcn_mfma_f32_16x16x32_bf16(av, b2[kk], cv2, 0, 0, 0);
    }
#pragma unroll
    for (int r = 0; r < 4; ++r) {
      int u = u0 + lg * 4 + r;
      float xsv = xrow[u];
      const float* xvu = xrow + 128 + 3 * u;
      out[(size_t)z * 512 + u] =
          0.0625f * xsv * css[r] +
          0.036084391824351615f * (cv0[r] * xvu[0] + cv1[r] * xvu[1] + cv2[r] * xvu[2]);
    }
  }
}

// ---------------- out_v -----------------------------------------------------
// grid 512 = 128 zb(64z) x 4 wc(32w); 2 blocks/CU. 8 waves = 4 zg(16z) x 2 wg.
// Phase (2 v): 2 gload16 + 3 xv uint loads (vmem=5), 8 ds_read_b128, 8 MFMA,
// 24 FMA per wave. 4 slots x 16KB rotation; stage T+3; wait vmcnt(10).

#define OUTV_PHASE(T_, CUR, STG, XC, XN)                                       \
  do {                                                                         \
    asm volatile("s_waitcnt vmcnt(10)" ::: "memory");                          \
    __builtin_amdgcn_s_barrier();                                              \
    __builtin_amdgcn_sched_barrier(0);                                         \
    {                                                                          \
      const int ts = (T_) + 3;                                                 \
      const ushort* sp = slab + (size_t)ts * 8192 + tid * 8;                   \
      gload16(sp,        lds + (STG) * 16384 + tid * 16);                      \
      gload16(sp + 4096, lds + (STG) * 16384 + 8192 + tid * 16);               \
      XN[0] = xq0[ts]; XN[1] = xq1[ts]; XN[2] = xq2[ts];                       \
    }                                                                          \
    __builtin_amdgcn_sched_barrier(0);                                         \
    const char* ab = lds + (CUR) * 16384 + wg * 4096 + l * 16;                 \
    _Pragma("unroll")                                                          \
    for (int vv = 0; vv < 2; ++vv) {                                           \
      bf16x8 a0 = *(const bf16x8*)(ab + vv * 8192);                            \
      bf16x8 a1 = *(const bf16x8*)(ab + vv * 8192 + 1024);                     \
      bf16x8 a2 = *(const bf16x8*)(ab + vv * 8192 + 2048);                     \
      bf16x8 a3 = *(const bf16x8*)(ab + vv * 8192 + 3072);                     \
      f32x4 tt = {0.f, 0.f, 0.f, 0.f};                                         \
      __builtin_amdgcn_s_setprio(1);                                           \
      tt = __builtin_amdgcn_mfma_f32_16x16x32_bf16(a0, b[0], tt, 0, 0, 0);     \
      tt = __builtin_amdgcn_mfma_f32_16x16x32_bf16(a1, b[1], tt, 0, 0, 0);     \
      tt = __builtin_amdgcn_mfma_f32_16x16x32_bf16(a2, b[2], tt, 0, 0, 0);     \
      tt = __builtin_amdgcn_mfma_f32_16x16x32_bf16(a3, b[3], tt, 0, 0, 0);     \
      __builtin_amdgcn_s_setprio(0);                                           \
      float x0, x1, x2;                                                        \
      if (vv == 0) {                                                           \
        x0 = __builtin_bit_cast(float, XC[0] << 16);                           \
        x1 = __builtin_bit_cast(float, XC[1] << 16);                           \
        x2 = __builtin_bit_cast(float, XC[2] << 16);                           \
      } else {                                                                 \
        x0 = __builtin_bit_cast(float, XC[0] & 0xffff0000u);                   \
        x1 = __builtin_bit_cast(float, XC[1] & 0xffff0000u);                   \
        x2 = __builtin_bit_cast(float, XC[2] & 0xffff0000u);                   \
      }                                                                        \
      _Pragma("unroll")                                                        \
      for (int r = 0; r < 4; ++r) {                                            \
        acc[r][0] += tt[r] * x0;                                               \
        acc[r][1] += tt[r] * x1;                                               \
        acc[r][2] += tt[r] * x2;                                               \
      }                                                                        \
    }                                                                          \
  } while (0)

__global__ __launch_bounds__(512, 4) void outv_kernel(
    const ushort* __restrict__ xs_bf, const ushort* __restrict__ xvq,
    const ushort* __restrict__ Wt, float* __restrict__ out) {
  extern __shared__ char lds[];      // 4 x 16KB
  int bid = blockIdx.x;
  int wc = bid & 3, zb = bid >> 2;
  int tid = threadIdx.x;
  int wid = tid >> 6, l = tid & 63;
  int wg = wid & 1, zg = wid >> 1;
  int lr = l & 15, lg = l >> 4;
  int z = zb * 64 + zg * 16 + lr;
  int w0 = wc * 32 + wg * 16;

  const ushort* slab = Wt + (size_t)wc * SLAB;
  const uint* xq0 = (const uint*)(xvq + ((size_t)0 * NZ + z) * 128);
  const uint* xq1 = (const uint*)(xvq + ((size_t)1 * NZ + z) * 128);
  const uint* xq2 = (const uint*)(xvq + ((size_t)2 * NZ + z) * 128);

  // B-fragments (xs), held all kernel: 4 k-chunks
  bf16x8 b[4];
#pragma unroll
  for (int kk = 0; kk < 4; ++kk)
    b[kk] = *(const bf16x8*)(xs_bf + (size_t)z * 128 + kk * 32 + lg * 8);
  __builtin_amdgcn_sched_barrier(0);

  // prologue: stage tiles 0,1,2 into slots 0,1,2 (+ xv uints)
  uint xa[3], xb[3], xc[3], xd[3];
#pragma unroll
  for (int p = 0; p < 3; ++p) {
    const ushort* sp = slab + (size_t)p * 8192 + tid * 8;
    gload16(sp,        lds + p * 16384 + tid * 16);
    gload16(sp + 4096, lds + p * 16384 + 8192 + tid * 16);
  }
  xa[0] = xq0[0]; xa[1] = xq1[0]; xa[2] = xq2[0];
  xb[0] = xq0[1]; xb[1] = xq1[1]; xb[2] = xq2[1];
  xc[0] = xq0[2]; xc[1] = xq1[2]; xc[2] = xq2[2];
  __builtin_amdgcn_sched_barrier(0);

  float acc[4][3] = {};

  for (int q = 0; q < 16; ++q) {
    OUTV_PHASE(4 * q + 0, 0, 3, xa, xd);
    OUTV_PHASE(4 * q + 1, 1, 0, xb, xa);
    OUTV_PHASE(4 * q + 2, 2, 1, xc, xb);
    OUTV_PHASE(4 * q + 3, 3, 2, xd, xc);
  }

#pragma unroll
  for (int r = 0; r < 4; ++r) {
    int w = w0 + lg * 4 + r;
    float* o = out + (size_t)z * 512 + 128 + 3 * w;
    o[0] = acc[r][0] * 0.0078125f;
    o[1] = acc[r][1] * 0.0078125f;
    o[2] = acc[r][2] * 0.0078125f;
  }
}

// ---------------- launch ----------------------------------------------------
extern "C" void kernel_launch(void* const* d_in, const int* in_sizes, int n_in,
                              void* d_out, int out_size, void* d_ws, size_t ws_size,
                              hipStream_t stream) {
  const float* x    = (const float*)d_in[0];
  const float* w_ss = (const float*)d_in[1];
  const float* w_sv = (const float*)d_in[2];
  const float* w_vv = (const float*)d_in[3];
  float* out = (float*)d_out;

  char* ws = (char*)d_ws;
  ushort* xs_bf = (ushort*)ws;                                  // 2 MB
  ushort* Wt    = (ushort*)(ws + (size_t)2 * 1024 * 1024);      // 4.19 MB (padded)
  ushort* xvq   = (ushort*)(ws + (size_t)6656 * 1024);          // 6 MB @ 6.5MB
  ushort* wssb  = (ushort*)(ws + (size_t)12800 * 1024);         // 32 KB @ 12.5MB
  ushort* wvvb  = (ushort*)(ws + (size_t)12800 * 1024 + 32768);

  prep_cast<<<384, 256, 0, stream>>>(x, w_ss, w_vv, xs_bf, xvq, wssb, wvvb);
  prep_wt<<<512, 256, 0, stream>>>(w_sv, Wt);
  outs_mfma<<<1024, 128, 0, stream>>>(x, xs_bf, wssb, wvvb, out);
  outv_kernel<<<512, 512, 65536, stream>>>(xs_bf, xvq, Wt, out);
}